// Round 8
// baseline (678.401 us; speedup 1.0000x reference)
//
#include <hip/hip_runtime.h>
#include <hip/hip_fp16.h>

// GIN_MLP: 2x GIN conv (N=100000, E=1.6M, H=128) + per-batch context MLP (B=4096).
// Device-built dst-CSR (rank-based atomic-free scatter, 8-aligned padded rows)
// -> fused aggregate+GEMM -> tiled final MLP.
// R19: conv gather via __builtin_amdgcn_global_load_lds (direct-to-LDS, zero
// destination VGPRs -- sidesteps the regalloc spills that killed R15/R17's
// wide-M attempts). Per wave: 8-edge batches, 2 x size=16 staging insts
// (64 lanes x 16B = 4 fp16 rows each) into a private 2-buffer LDS ring;
// descriptors in 2 rotating int4x4 reg sets (R14 broadcast pattern); counted
// s_waitcnt vmcnt(6) + sched_barrier before consume (rule #18); lgkmcnt(0)
// fence before restaging a just-read buffer. Consume: 4 ds_read_b64/lane
// (2-way alias = free) + cvt + FMA, natural-layout acc -> permute pass gone.
// LDS 16.4K(xm)+16K(stg) -> 4 blocks/CU (occupancy second-order: R12).

#define CONV_NPB 32
#define FIN_EPB 8

struct __align__(8)  h4 { __half2 a, b; };
struct __align__(16) h8 { __half2 a, b, c, d; };

__device__ __forceinline__ float4 h4f(h4 u) {
  return make_float4(__low2float(u.a), __high2float(u.a),
                     __low2float(u.b), __high2float(u.b));
}
__device__ __forceinline__ h4 f4h(float4 v) {
  h4 u; u.a = __floats2half2_rn(v.x, v.y); u.b = __floats2half2_rn(v.z, v.w);
  return u;
}

// select among 4 by lane-group (compiles to cndmask tree; indices static)
#define SEL4(g, a, b, c, d) ((g) < 2 ? ((g) == 0 ? (a) : (b)) : ((g) == 2 ? (c) : (d)))

// direct global->LDS staging, 16B/lane (64 lanes = 1024B). lds ptr wave-uniform.
__device__ __forceinline__ void stage16(const __half* gp, const __half* lp) {
  __builtin_amdgcn_global_load_lds(
      (const __attribute__((address_space(1))) unsigned int*)(unsigned long long)(const void*)gp,
      (__attribute__((address_space(3))) unsigned int*)(unsigned int)(unsigned long long)(const void*)lp,
      16, 0, 0);
}

// merged init+hist (R18, proven-neutral-safe): weight transposes + fp16 cast
// of ndata + per-dst degree & per-edge rank. cnt zeroed by hipMemsetAsync.
__global__ void inithist_kernel(const float* __restrict__ W1, const float* __restrict__ W2,
                                const float* __restrict__ Wc1, const float* __restrict__ Wc2,
                                const float* __restrict__ ndata, __half* __restrict__ xh0,
                                float* __restrict__ Wt1, float* __restrict__ Wt2,
                                float* __restrict__ Wc1t, float* __restrict__ Wc2t,
                                const int* __restrict__ dst, int* __restrict__ cnt,
                                int* __restrict__ rank, int n, int E) {
  int i = blockIdx.x * blockDim.x + threadIdx.x;
  int e = i * 4;
  if (e + 3 < E) {
    const int4 d = *(const int4*)&dst[e];
    int4 r;
    r.x = atomicAdd(&cnt[d.x], 1);
    r.y = atomicAdd(&cnt[d.y], 1);
    r.z = atomicAdd(&cnt[d.z], 1);
    r.w = atomicAdd(&cnt[d.w], 1);
    *(int4*)&rank[e] = r;
  } else {
    for (; e < E; ++e) rank[e] = atomicAdd(&cnt[dst[e]], 1);
  }
  const int cbase = i * 8;
  if (cbase < n * 128) {
    const float4 v0 = *(const float4*)&ndata[cbase];
    const float4 v1 = *(const float4*)&ndata[cbase + 4];
    h8 u;
    u.a = __floats2half2_rn(v0.x, v0.y);
    u.b = __floats2half2_rn(v0.z, v0.w);
    u.c = __floats2half2_rn(v1.x, v1.y);
    u.d = __floats2half2_rn(v1.z, v1.w);
    *(h8*)&xh0[cbase] = u;
  }
  if (i < 16384) {
    int f = i >> 7, k = i & 127;
    Wt1[k * 128 + f] = W1[i];
  } else if (i < 32768) {
    int j = i - 16384; int f = j >> 7, k = j & 127;
    Wt2[k * 128 + f] = W2[j];
  } else if (i < 81920) {
    int j = i - 32768; int f = j / 384, k = j % 384;
    Wc1t[k * 128 + f] = Wc1[j];
  } else if (i < 90112) {
    int j = i - 81920; int f = j >> 7, k = j & 127;
    Wc2t[k * 64 + f] = Wc2[j];
  }
}

// per-2048-chunk exclusive scan of PADDED counts (ceil(cnt/8)*8); bsum[b] = chunk total
__global__ void scan1_kernel(const int* __restrict__ cnt, int* __restrict__ prow,
                             int* __restrict__ bsum, int n) {
  __shared__ int smem[256];
  const int t = threadIdx.x;
  const int base = blockIdx.x * 2048 + t * 8;
  int v[8];
  int s = 0;
#pragma unroll
  for (int j = 0; j < 8; ++j) {
    int idx = base + j;
    v[j] = (idx < n) ? ((cnt[idx] + 7) & ~7) : 0;
    s += v[j];
  }
  smem[t] = s;
  __syncthreads();
  for (int off = 1; off < 256; off <<= 1) {
    int add = (t >= off) ? smem[t - off] : 0;
    __syncthreads();
    smem[t] += add;
    __syncthreads();
  }
  int run = smem[t] - s;
  if (t == 255) bsum[blockIdx.x] = smem[255];
#pragma unroll
  for (int j = 0; j < 8; ++j) {
    int idx = base + j;
    if (idx < n) prow[idx] = run;
    run += v[j];
  }
}

// 64-lane shuffle scan (nchunk=49 fits); appends grand total at bsum[nb]
__global__ void scan2_kernel(int* __restrict__ bsum, int nb) {
  const int t = threadIdx.x;
  if (nb <= 64) {
    const int orig = (t < nb) ? bsum[t] : 0;
    int v = orig;
#pragma unroll
    for (int off = 1; off < 64; off <<= 1) {
      int u = __shfl_up(v, off);
      if (t >= off) v += u;
    }
    if (t == nb - 1) bsum[nb] = v;
    if (t < nb) bsum[t] = v - orig;
  } else if (t == 0) {
    int run = 0;
    for (int i = 0; i < nb; ++i) { int v = bsum[i]; bsum[i] = run; run += v; }
    bsum[nb] = run;
  }
}

// atomic-free scatter into padded CSR, 4 edges/thread; threads i<n also zero
// their node's pad slots (real + pad slots exactly partition the padded CSR)
__global__ void scatter_kernel(const int* __restrict__ src, const int* __restrict__ dst,
                               const float* __restrict__ w, const int* __restrict__ prow,
                               const int* __restrict__ bsum, const int* __restrict__ rank,
                               const int* __restrict__ cnt,
                               int2* __restrict__ epack, int E, int n) {
  const int i = blockIdx.x * blockDim.x + threadIdx.x;
  int e = i * 4;
  if (e + 3 < E) {
    const int4 d = *(const int4*)&dst[e];
    const int4 s = *(const int4*)&src[e];
    const float4 wv = *(const float4*)&w[e];
    const int4 r = *(const int4*)&rank[e];
    epack[prow[d.x] + bsum[d.x >> 11] + r.x] = make_int2(s.x, __float_as_int(wv.x));
    epack[prow[d.y] + bsum[d.y >> 11] + r.y] = make_int2(s.y, __float_as_int(wv.y));
    epack[prow[d.z] + bsum[d.z >> 11] + r.z] = make_int2(s.z, __float_as_int(wv.z));
    epack[prow[d.w] + bsum[d.w >> 11] + r.w] = make_int2(s.w, __float_as_int(wv.w));
  } else {
    for (; e < E; ++e) {
      const int d = dst[e];
      epack[prow[d] + bsum[d >> 11] + rank[e]] = make_int2(src[e], __float_as_int(w[e]));
    }
  }
  if (i < n) {
    const int c = cnt[i];
    const int start = prow[i] + bsum[i >> 11] + c;
    const int pc = ((c + 7) & ~7) - c;
    for (int j = 0; j < pc; ++j) epack[start + j] = make_int2(0, 0);
  }
}

// issue one 8-edge batch's staging: 2 x stage16 (edges 0-3, 4-7)
#define ISSUE_STG(qa, qb, qc, qd, lbase) do {                              \
    const int _s0 = SEL4(grp, (qa).x, (qa).z, (qb).x, (qb).z);             \
    const int _s1 = SEL4(grp, (qc).x, (qc).z, (qd).x, (qd).z);             \
    stage16(&xinh[(size_t)_s0 * 128 + sub * 8], (lbase));                  \
    stage16(&xinh[(size_t)_s1 * 128 + sub * 8], (lbase) + 512);            \
  } while (0)

#define FLUSHACC() do {                                                    \
    float* _bp = &xm[r * 128 + fg * 4];                                    \
    atomicAdd(_bp + 0, acc.x); atomicAdd(_bp + 1, acc.y);                  \
    atomicAdd(_bp + 2, acc.z); atomicAdd(_bp + 3, acc.w);                  \
    acc = make_float4(0.f, 0.f, 0.f, 0.f);                                 \
  } while (0)

// consume batch from LDS buffer sc with weights from q descriptors
#define CONSUME(q0_, q1_, q2_, q3_, sc) do {                               \
    const float w0 = __int_as_float(hi ? (q0_).w : (q0_).y);               \
    const float w1 = __int_as_float(hi ? (q1_).w : (q1_).y);               \
    const float w2 = __int_as_float(hi ? (q2_).w : (q2_).y);               \
    const float w3 = __int_as_float(hi ? (q3_).w : (q3_).y);               \
    const h4 u0 = *(const h4*)&(sc)[(0 + hi) * 128 + fg * 4];              \
    const h4 u1 = *(const h4*)&(sc)[(2 + hi) * 128 + fg * 4];              \
    const h4 u2 = *(const h4*)&(sc)[(4 + hi) * 128 + fg * 4];              \
    const h4 u3 = *(const h4*)&(sc)[(6 + hi) * 128 + fg * 4];              \
    asm volatile("s_waitcnt lgkmcnt(0)" ::: "memory");                     \
    __builtin_amdgcn_sched_barrier(0);                                     \
    const float4 a0 = h4f(u0), a1 = h4f(u1), a2 = h4f(u2), a3 = h4f(u3);   \
    acc.x += w0 * a0.x + w1 * a1.x + w2 * a2.x + w3 * a3.x;                \
    acc.y += w0 * a0.y + w1 * a1.y + w2 * a2.y + w3 * a3.y;                \
    acc.z += w0 * a0.z + w1 * a1.z + w2 * a2.z + w3 * a3.z;                \
    acc.w += w0 * a0.w + w1 * a1.w + w2 * a2.w + w3 * a3.w;                \
  } while (0)

// R19 conv. Stage 1: per-wave chunk of 8-edge batches (8-aligned padding
// guarantees each batch lies in ONE dst row). Double-buffered direct-to-LDS
// staging; per batch: 2 stage16 + 4 desc loads + 4 ds_read_b64/lane + cvt/FMA.
// acc (float4, natural feature layout) flushes to xm via LDS atomics only at
// row transitions. Stage 2: in-place (1+eps)x + agg/deg. Stage 3: GEMM f32.
__launch_bounds__(256, 4)
__global__ void conv_kernel(const float* __restrict__ xin, const __half* __restrict__ xinh,
                            float* __restrict__ xout, __half* __restrict__ xouth,
                            const int* __restrict__ prow, const int* __restrict__ bsum,
                            const int* __restrict__ cnt,
                            const int2* __restrict__ epack,
                            const float* __restrict__ Wt,
                            const float* __restrict__ bias, const float* __restrict__ eps,
                            int epsidx, int dorelu, int zerorow0, int writef32,
                            int n, int nchunk) {
  __shared__ float xm[CONV_NPB * 128];
  __shared__ __half stg[4][2][1024];     // 4 waves x 2 bufs x 8 rows x 128 halves
  __shared__ int rp_s[CONV_NPB + 1];
  const int t = threadIdx.x;
  const int nb = blockIdx.x * CONV_NPB;
  const float epsv = 1.0f + eps[epsidx];

#pragma unroll
  for (int i = 0; i < 4; ++i)
    *(float4*)&xm[(t + i * 256) * 4] = make_float4(0.f, 0.f, 0.f, 0.f);
  if (t <= CONV_NPB) {
    const int node = nb + t;
    rp_s[t] = (node >= n) ? bsum[nchunk] : (prow[node] + bsum[node >> 11]);
  }
  __syncthreads();

  // ---- stage 1: direct-to-LDS double-buffered pipeline ----
  {
    const int wid = t >> 6;
    const int lane = t & 63;
    const int grp = lane >> 4;          // staging: row within inst (0..3)
    const int sub = lane & 15;          // staging: 16B chunk within row
    const int fg = lane & 31;           // consume: feature group (4 feats)
    const int hi = lane >> 5;           // consume: edge parity (half-wave)
    const int e0 = rp_s[0], eT = rp_s[CONV_NPB];
    const int nbat = (eT - e0) >> 3;
    const int cw = (nbat + 3) >> 2;     // batches per wave
    const int b0w = wid * cw;
    const int bend = min(b0w + cw, nbat);
    if (b0w < bend) {
      const int4* ep4 = (const int4*)epack;
      const int hbase = e0 >> 1;        // int4 index of edge e0
      __half* s0 = &stg[wid][0][0];
      __half* s1 = &stg[wid][1][0];
      int r = 0;
      { const int j0 = e0 + b0w * 8; while (rp_s[r + 1] <= j0) ++r; }
      float4 acc = make_float4(0.f, 0.f, 0.f, 0.f);

      // prologue: descriptors for first two batches, stage both buffers
      int hE = hbase + b0w * 4;
      int4 qE0 = ep4[hE], qE1 = ep4[hE + 1], qE2 = ep4[hE + 2], qE3 = ep4[hE + 3];
      const int b1c = (b0w + 1 < bend) ? (b0w + 1) : b0w;
      int hO = hbase + b1c * 4;
      int4 qO0 = ep4[hO], qO1 = ep4[hO + 1], qO2 = ep4[hO + 2], qO3 = ep4[hO + 3];
      ISSUE_STG(qE0, qE1, qE2, qE3, s0);
      ISSUE_STG(qO0, qO1, qO2, qO3, s1);

      for (int b = b0w; b < bend; b += 2) {
        // ======== even batch b : buffer s0, descriptors qE ========
        {
          // prefetch desc(b+2) into qE (weights for b extracted inside CONSUME
          // need qE *before* overwrite -> copy the 4 weight words first)
          const int4 qc0 = qE0, qc1 = qE1, qc2 = qE2, qc3 = qE3;
          const int bn = (b + 2 < bend) ? (b + 2) : b;
          const int hN = hbase + bn * 4;
          qE0 = ep4[hN]; qE1 = ep4[hN + 1]; qE2 = ep4[hN + 2]; qE3 = ep4[hN + 3];
          // ensure batch b's staging landed (<=6 newer allowed: stg b+1 + desc)
          asm volatile("s_waitcnt vmcnt(6)" ::: "memory");
          __builtin_amdgcn_sched_barrier(0);
          const int j = e0 + b * 8;
          if (rp_s[r + 1] <= j) {
            FLUSHACC();
            do { ++r; } while (rp_s[r + 1] <= j);
          }
          CONSUME(qc0, qc1, qc2, qc3, s0);
          // s0 fully read (lgkmcnt(0) inside CONSUME) -> restage for b+2
          ISSUE_STG(qE0, qE1, qE2, qE3, s0);
        }
        // ======== odd batch b+1 : buffer s1, descriptors qO ========
        if (b + 1 < bend) {
          const int4 qc0 = qO0, qc1 = qO1, qc2 = qO2, qc3 = qO3;
          const int bn = (b + 3 < bend) ? (b + 3) : (b + 1);
          const int hN = hbase + bn * 4;
          qO0 = ep4[hN]; qO1 = ep4[hN + 1]; qO2 = ep4[hN + 2]; qO3 = ep4[hN + 3];
          asm volatile("s_waitcnt vmcnt(6)" ::: "memory");
          __builtin_amdgcn_sched_barrier(0);
          const int j = e0 + (b + 1) * 8;
          if (rp_s[r + 1] <= j) {
            FLUSHACC();
            do { ++r; } while (rp_s[r + 1] <= j);
          }
          CONSUME(qc0, qc1, qc2, qc3, s1);
          ISSUE_STG(qO0, qO1, qO2, qO3, s1);
        }
      }
      FLUSHACC();
      // drain our outstanding staging loads before the block-wide barrier
      asm volatile("s_waitcnt vmcnt(0)" ::: "memory");
    }
  }
  __syncthreads();

  // ---- stage 2: in-place finalize (1+eps)*x + agg/deg (natural layout) ----
  {
#pragma unroll
    for (int q = 0; q < 4; ++q) {
      const int task = t + q * 256;
      const int r = task >> 5;
      const int fg = task & 31;
      const int f0 = fg * 4;
      const int node = nb + r;
      float4 v = make_float4(0.f, 0.f, 0.f, 0.f);
      if (node < n) {
        const int d = cnt[node];
        const float rdeg = 1.0f / (float)(d > 1 ? d : 1);
        const float4 xv = *(const float4*)&xin[(size_t)node * 128 + f0];
        const float4 m = *(const float4*)&xm[r * 128 + f0];
        v.x = epsv * xv.x + m.x * rdeg;
        v.y = epsv * xv.y + m.y * rdeg;
        v.z = epsv * xv.z + m.z * rdeg;
        v.w = epsv * xv.w + m.w * rdeg;
      }
      *(float4*)&xm[r * 128 + f0] = v;   // each (r,f0) owned by one thread
    }
  }
  __syncthreads();

  // ---- stage 3: GEMM, thread tile = 4 rows x 4 features ----
  {
    const int fg = t & 31;
    const int rg = t >> 5;
    const int f0 = fg * 4;
    const int r0 = rg * 4;
    float4 acc[4];
#pragma unroll
    for (int r = 0; r < 4; ++r) acc[r] = make_float4(0.f, 0.f, 0.f, 0.f);
    for (int k = 0; k < 128; k += 4) {
      const float4 w0 = *(const float4*)&Wt[(k + 0) * 128 + f0];
      const float4 w1 = *(const float4*)&Wt[(k + 1) * 128 + f0];
      const float4 w2 = *(const float4*)&Wt[(k + 2) * 128 + f0];
      const float4 w3 = *(const float4*)&Wt[(k + 3) * 128 + f0];
#pragma unroll
      for (int r = 0; r < 4; ++r) {
        const float4 xv = *(const float4*)&xm[(r0 + r) * 128 + k];
        acc[r].x += xv.x * w0.x + xv.y * w1.x + xv.z * w2.x + xv.w * w3.x;
        acc[r].y += xv.x * w0.y + xv.y * w1.y + xv.z * w2.y + xv.w * w3.y;
        acc[r].z += xv.x * w0.z + xv.y * w1.z + xv.z * w2.z + xv.w * w3.z;
        acc[r].w += xv.x * w0.w + xv.y * w1.w + xv.z * w2.w + xv.w * w3.w;
      }
    }
    const float4 bv = *(const float4*)&bias[f0];
#pragma unroll
    for (int r = 0; r < 4; ++r) {
      const int node = nb + r0 + r;
      if (node < n) {
        float4 v;
        v.x = acc[r].x + bv.x;
        v.y = acc[r].y + bv.y;
        v.z = acc[r].z + bv.z;
        v.w = acc[r].w + bv.w;
        if (dorelu) {
          v.x = fmaxf(v.x, 0.f); v.y = fmaxf(v.y, 0.f);
          v.z = fmaxf(v.z, 0.f); v.w = fmaxf(v.w, 0.f);
        }
        if (zerorow0 && node == 0) { v.x = 0.f; v.y = 0.f; v.z = 0.f; v.w = 0.f; }
        *(h4*)&xouth[(size_t)node * 128 + f0] = f4h(v);
        if (writef32) *(float4*)&xout[(size_t)node * 128 + f0] = v;
      }
    }
  }
}

// Final MLP: 8 elems per 256-thread block (512 blocks); x2 gathers in fp16.
__launch_bounds__(256, 4)
__global__ void final_kernel(const __half* __restrict__ x2h, const int* __restrict__ indices,
                             const float* __restrict__ Wc1t, const float* __restrict__ bc1,
                             const float* __restrict__ Wc2t, const float* __restrict__ bc2,
                             const float* __restrict__ Wc3, const float* __restrict__ bc3,
                             float* __restrict__ out) {
  __shared__ float ysm[FIN_EPB * 384];
  __shared__ float h1s[FIN_EPB * 128];
  __shared__ float h2s[FIN_EPB * 64];
  __shared__ int ind_s[FIN_EPB * 23];
  __shared__ float ccs[FIN_EPB];
  const int t = threadIdx.x;
  const int b0 = blockIdx.x * FIN_EPB;

  if (t < FIN_EPB * 23) ind_s[t] = indices[(size_t)b0 * 23 + t];
  __syncthreads();
  if (t < FIN_EPB) {
    int cc = 0;
#pragma unroll
    for (int j = 0; j < 20; ++j) cc += (ind_s[t * 23 + 3 + j] > 0) ? 1 : 0;
    ccs[t] = 1.0f / (float)(cc > 0 ? cc : 1);
  }
  __syncthreads();

  // ---- phase A ----
  {
#pragma unroll
    for (int q = 0; q < 2; ++q) {
      const int s = t + q * 256;
      const int e = s >> 6;
      const int hf = (s >> 5) & 1;
      const int fg = s & 31;
      const int idx = ind_s[e * 23 + hf];
      const h4 u = *(const h4*)&x2h[(size_t)idx * 128 + fg * 4];
      *(float4*)&ysm[e * 384 + hf * 128 + fg * 4] = h4f(u);
    }
    const int e = t >> 5;
    const int fg = t & 31;
    float4 acc = make_float4(0.f, 0.f, 0.f, 0.f);
#pragma unroll
    for (int j = 0; j < 20; ++j) {
      const int cj = ind_s[e * 23 + 3 + j];
      const h4 u = *(const h4*)&x2h[(size_t)cj * 128 + fg * 4];
      const float4 a = h4f(u);
      acc.x += a.x; acc.y += a.y; acc.z += a.z; acc.w += a.w;
    }
    const float sc = ccs[e];
    acc.x *= sc; acc.y *= sc; acc.z *= sc; acc.w *= sc;
    *(float4*)&ysm[e * 384 + 256 + fg * 4] = acc;
  }
  __syncthreads();

  // ---- phase B: layer 1 (384 -> 128), 4 elems per thread ----
  {
    const int f1 = t & 127;
    const int eh = t >> 7;
    float acc[4];
    const float b = bc1[f1];
#pragma unroll
    for (int i = 0; i < 4; ++i) acc[i] = b;
    for (int k = 0; k < 384; k += 4) {
      const float wv0 = Wc1t[(k + 0) * 128 + f1];
      const float wv1 = Wc1t[(k + 1) * 128 + f1];
      const float wv2 = Wc1t[(k + 2) * 128 + f1];
      const float wv3 = Wc1t[(k + 3) * 128 + f1];
#pragma unroll
      for (int i = 0; i < 4; ++i) {
        const float4 yv = *(const float4*)&ysm[(eh * 4 + i) * 384 + k];
        acc[i] += yv.x * wv0 + yv.y * wv1 + yv.z * wv2 + yv.w * wv3;
      }
    }
#pragma unroll
    for (int i = 0; i < 4; ++i)
      h1s[(eh * 4 + i) * 128 + f1] = fmaxf(acc[i], 0.f);
  }
  __syncthreads();

  // ---- phase C: layer 2 (128 -> 64), 2 elems per thread ----
  {
    const int f2 = t & 63;
    const int eg = t >> 6;
    float acc[2];
    const float b = bc2[f2];
#pragma unroll
    for (int i = 0; i < 2; ++i) acc[i] = b;
    for (int k = 0; k < 128; k += 4) {
      const float wv0 = Wc2t[(k + 0) * 64 + f2];
      const float wv1 = Wc2t[(k + 1) * 64 + f2];
      const float wv2 = Wc2t[(k + 2) * 64 + f2];
      const float wv3 = Wc2t[(k + 3) * 64 + f2];
#pragma unroll
      for (int i = 0; i < 2; ++i) {
        const float4 hv = *(const float4*)&h1s[(eg * 2 + i) * 128 + k];
        acc[i] += hv.x * wv0 + hv.y * wv1 + hv.z * wv2 + hv.w * wv3;
      }
    }
#pragma unroll
    for (int i = 0; i < 2; ++i)
      h2s[(eg * 2 + i) * 64 + f2] = fmaxf(acc[i], 0.f);
  }
  __syncthreads();

  // ---- phase D: layer 3 (64 -> 1), 32 lanes per element ----
  {
    const int e = t >> 5;
    const int l = t & 31;
    float p = h2s[e * 64 + l] * Wc3[l] + h2s[e * 64 + l + 32] * Wc3[l + 32];
#pragma unroll
    for (int o = 16; o > 0; o >>= 1) p += __shfl_down(p, o, 32);
    if (l == 0) out[b0 + e] = p + bc3[0];
  }
}

extern "C" void kernel_launch(void* const* d_in, const int* in_sizes, int n_in,
                              void* d_out, int out_size, void* d_ws, size_t ws_size,
                              hipStream_t stream) {
  const int* indices = (const int*)d_in[0];
  const int* src = (const int*)d_in[1];
  const int* dst = (const int*)d_in[2];
  const float* w = (const float*)d_in[3];
  const float* ndata = (const float*)d_in[4];
  const float* W1 = (const float*)d_in[5];
  const float* b1 = (const float*)d_in[6];
  const float* W2 = (const float*)d_in[7];
  const float* b2 = (const float*)d_in[8];
  const float* eps = (const float*)d_in[9];
  const float* Wc1 = (const float*)d_in[10];
  const float* bc1 = (const float*)d_in[11];
  const float* Wc2 = (const float*)d_in[12];
  const float* bc2 = (const float*)d_in[13];
  const float* Wc3 = (const float*)d_in[14];
  const float* bc3 = (const float*)d_in[15];
  float* out = (float*)d_out;

  const int E = in_sizes[1];
  const int N = in_sizes[4] / 128;
  const int B = in_sizes[0] / 23;

  char* ws = (char*)d_ws;
  size_t off = 0;
  auto alloc = [&](size_t bytes) -> char* {
    char* p = ws + off;
    off = (off + bytes + 255) & ~(size_t)255;
    return p;
  };
  const size_t Epad = (size_t)E + 8 * (size_t)N;   // worst-case padded edge count
  int* cnt = (int*)alloc((size_t)N * 4);
  int* prow = (int*)alloc((size_t)(N + 1) * 4);
  int* rank = (int*)alloc((size_t)E * 4);
  int* bsum = (int*)alloc(256 * 4);
  int2* epack = (int2*)alloc(Epad * 8);
  float* x1 = (float*)alloc((size_t)N * 128 * 4);          // f32 x1 (conv2 self term)
  __half* xh0 = (__half*)alloc((size_t)N * 128 * 2);       // fp16 ndata; reused as x2h
  __half* x1h = (__half*)alloc((size_t)N * 128 * 2);       // fp16 x1 (conv2 gathers)
  float* Wt1 = (float*)alloc(16384 * 4);
  float* Wt2 = (float*)alloc(16384 * 4);
  float* Wc1t = (float*)alloc(49152 * 4);
  float* Wc2t = (float*)alloc(8192 * 4);
  __half* x2h = xh0;   // xh0 dead after conv1; conv2 writes x2 (fp16) here

  // cnt = 0 (stream-ordered; completes before inithist's atomics)
  hipMemsetAsync(cnt, 0, (size_t)N * 4, stream);

  const int ncast = (N * 128 + 7) / 8;                     // 1.6M cast threads
  const int Eq = (E + 3) / 4;
  int ninit = (N > 90112) ? N : 90112;
  if (ncast > ninit) ninit = ncast;
  if (Eq > ninit) ninit = Eq;
  inithist_kernel<<<(ninit + 255) / 256, 256, 0, stream>>>(
      W1, W2, Wc1, Wc2, ndata, xh0, Wt1, Wt2, Wc1t, Wc2t, dst, cnt, rank, N, E);

  const int nchunk = (N + 2047) / 2048;
  scan1_kernel<<<nchunk, 256, 0, stream>>>(cnt, prow, bsum, N);
  scan2_kernel<<<1, 64, 0, stream>>>(bsum, nchunk);
  const int nsc = (Eq > N) ? Eq : N;
  scatter_kernel<<<(nsc + 255) / 256, 256, 0, stream>>>(src, dst, w, prow, bsum, rank, cnt, epack, E, N);

  const int nconv = (N + CONV_NPB - 1) / CONV_NPB;
  // conv1: gathers fp16(ndata), self term f32 ndata; writes x1 (f32) + x1h (fp16)
  conv_kernel<<<nconv, 256, 0, stream>>>(ndata, xh0, x1, x1h, prow, bsum, cnt, epack,
                                         Wt1, b1, eps, 0, 1, 0, 1, N, nchunk);
  // conv2: gathers x1h, self term f32 x1; writes x2h (fp16 only, into xh0 buffer)
  conv_kernel<<<nconv, 256, 0, stream>>>(x1, x1h, nullptr, x2h, prow, bsum, cnt, epack,
                                         Wt2, b2, eps, 1, 0, 1, 0, N, nchunk);

  final_kernel<<<B / FIN_EPB, 256, 0, stream>>>(x2h, indices, Wc1t, bc1, Wc2t, bc2, Wc3, bc3, out);
}

// Round 9
// 511.822 us; speedup vs baseline: 1.3255x; 1.3255x over previous
//
#include <hip/hip_runtime.h>
#include <hip/hip_fp16.h>

// GIN_MLP: 2x GIN conv (N=100000, E=1.6M, H=128) + per-batch context MLP (B=4096).
// Device-built dst-CSR (rank-based atomic-free scatter, 8-aligned padded rows)
// -> fused aggregate+GEMM -> tiled final MLP.
// R20: consolidation after four failed M>8 attempts (R15/R16/R17/R19: spills
// or waitcnt serialization; conv obeys T=84+496/M and M=8 register gathers is
// the practical HIP-level floor at 146-148us). conv stage-1 is R14 verbatim.
// New: f32 x1 eliminated -- conv2's self term reads x1h (fp16), so conv1
// writes only fp16 (-51MB write) and conv2 stage-2 fetches 26MB not 51MB.
// All-fp16 state: ndata16 -> conv1 -> x1h -> conv2 -> x2h -> final MLP.

#define CONV_NPB 32
#define FIN_EPB 8

struct __align__(8)  h4 { __half2 a, b; };
struct __align__(16) h8 { __half2 a, b, c, d; };

__device__ __forceinline__ float4 h4f(h4 u) {
  return make_float4(__low2float(u.a), __high2float(u.a),
                     __low2float(u.b), __high2float(u.b));
}
__device__ __forceinline__ h4 f4h(float4 v) {
  h4 u; u.a = __floats2half2_rn(v.x, v.y); u.b = __floats2half2_rn(v.z, v.w);
  return u;
}

// merged init+hist (R18, proven): weight transposes + fp16 cast of ndata
// + per-dst degree & per-edge rank. cnt zeroed by hipMemsetAsync before.
__global__ void inithist_kernel(const float* __restrict__ W1, const float* __restrict__ W2,
                                const float* __restrict__ Wc1, const float* __restrict__ Wc2,
                                const float* __restrict__ ndata, __half* __restrict__ xh0,
                                float* __restrict__ Wt1, float* __restrict__ Wt2,
                                float* __restrict__ Wc1t, float* __restrict__ Wc2t,
                                const int* __restrict__ dst, int* __restrict__ cnt,
                                int* __restrict__ rank, int n, int E) {
  int i = blockIdx.x * blockDim.x + threadIdx.x;
  int e = i * 4;
  if (e + 3 < E) {
    const int4 d = *(const int4*)&dst[e];
    int4 r;
    r.x = atomicAdd(&cnt[d.x], 1);
    r.y = atomicAdd(&cnt[d.y], 1);
    r.z = atomicAdd(&cnt[d.z], 1);
    r.w = atomicAdd(&cnt[d.w], 1);
    *(int4*)&rank[e] = r;
  } else {
    for (; e < E; ++e) rank[e] = atomicAdd(&cnt[dst[e]], 1);
  }
  const int cbase = i * 8;
  if (cbase < n * 128) {
    const float4 v0 = *(const float4*)&ndata[cbase];
    const float4 v1 = *(const float4*)&ndata[cbase + 4];
    h8 u;
    u.a = __floats2half2_rn(v0.x, v0.y);
    u.b = __floats2half2_rn(v0.z, v0.w);
    u.c = __floats2half2_rn(v1.x, v1.y);
    u.d = __floats2half2_rn(v1.z, v1.w);
    *(h8*)&xh0[cbase] = u;
  }
  if (i < 16384) {
    int f = i >> 7, k = i & 127;
    Wt1[k * 128 + f] = W1[i];
  } else if (i < 32768) {
    int j = i - 16384; int f = j >> 7, k = j & 127;
    Wt2[k * 128 + f] = W2[j];
  } else if (i < 81920) {
    int j = i - 32768; int f = j / 384, k = j % 384;
    Wc1t[k * 128 + f] = Wc1[j];
  } else if (i < 90112) {
    int j = i - 81920; int f = j >> 7, k = j & 127;
    Wc2t[k * 64 + f] = Wc2[j];
  }
}

// per-2048-chunk exclusive scan of PADDED counts (ceil(cnt/8)*8); bsum[b] = chunk total
__global__ void scan1_kernel(const int* __restrict__ cnt, int* __restrict__ prow,
                             int* __restrict__ bsum, int n) {
  __shared__ int smem[256];
  const int t = threadIdx.x;
  const int base = blockIdx.x * 2048 + t * 8;
  int v[8];
  int s = 0;
#pragma unroll
  for (int j = 0; j < 8; ++j) {
    int idx = base + j;
    v[j] = (idx < n) ? ((cnt[idx] + 7) & ~7) : 0;
    s += v[j];
  }
  smem[t] = s;
  __syncthreads();
  for (int off = 1; off < 256; off <<= 1) {
    int add = (t >= off) ? smem[t - off] : 0;
    __syncthreads();
    smem[t] += add;
    __syncthreads();
  }
  int run = smem[t] - s;
  if (t == 255) bsum[blockIdx.x] = smem[255];
#pragma unroll
  for (int j = 0; j < 8; ++j) {
    int idx = base + j;
    if (idx < n) prow[idx] = run;
    run += v[j];
  }
}

// 64-lane shuffle scan (nchunk=49 fits); appends grand total at bsum[nb]
__global__ void scan2_kernel(int* __restrict__ bsum, int nb) {
  const int t = threadIdx.x;
  if (nb <= 64) {
    const int orig = (t < nb) ? bsum[t] : 0;
    int v = orig;
#pragma unroll
    for (int off = 1; off < 64; off <<= 1) {
      int u = __shfl_up(v, off);
      if (t >= off) v += u;
    }
    if (t == nb - 1) bsum[nb] = v;
    if (t < nb) bsum[t] = v - orig;
  } else if (t == 0) {
    int run = 0;
    for (int i = 0; i < nb; ++i) { int v = bsum[i]; bsum[i] = run; run += v; }
    bsum[nb] = run;
  }
}

// atomic-free scatter into padded CSR, 4 edges/thread; threads i<n also zero
// their node's pad slots (real + pad slots exactly partition the padded CSR)
__global__ void scatter_kernel(const int* __restrict__ src, const int* __restrict__ dst,
                               const float* __restrict__ w, const int* __restrict__ prow,
                               const int* __restrict__ bsum, const int* __restrict__ rank,
                               const int* __restrict__ cnt,
                               int2* __restrict__ epack, int E, int n) {
  const int i = blockIdx.x * blockDim.x + threadIdx.x;
  int e = i * 4;
  if (e + 3 < E) {
    const int4 d = *(const int4*)&dst[e];
    const int4 s = *(const int4*)&src[e];
    const float4 wv = *(const float4*)&w[e];
    const int4 r = *(const int4*)&rank[e];
    epack[prow[d.x] + bsum[d.x >> 11] + r.x] = make_int2(s.x, __float_as_int(wv.x));
    epack[prow[d.y] + bsum[d.y >> 11] + r.y] = make_int2(s.y, __float_as_int(wv.y));
    epack[prow[d.z] + bsum[d.z >> 11] + r.z] = make_int2(s.z, __float_as_int(wv.z));
    epack[prow[d.w] + bsum[d.w >> 11] + r.w] = make_int2(s.w, __float_as_int(wv.w));
  } else {
    for (; e < E; ++e) {
      const int d = dst[e];
      epack[prow[d] + bsum[d >> 11] + rank[e]] = make_int2(src[e], __float_as_int(w[e]));
    }
  }
  if (i < n) {
    const int c = cnt[i];
    const int start = prow[i] + bsum[i >> 11] + c;
    const int pc = ((c + 7) & ~7) - c;
    for (int j = 0; j < pc; ++j) epack[start + j] = make_int2(0, 0);
  }
}

// Stage 1 (R14, proven): block's 32 rows = contiguous 8-aligned padded edge
// range, split into 8 laneset chunks. Per 8-edge batch: 8 independent 8B
// fp16-row gathers (from PREFETCHED descriptors; 2 cache lines per edge) +
// prefetch of next batch's 4 int4 descriptors + cvt + 32 FMA. Register acc
// flushes to LDS (permuted, bank=lane) only at row transitions. 8 blocks/CU.
// Stage 2: de-permute + (1+eps)x + agg/deg; self term from f32 xinf (conv1)
// or fp16 xinh (conv2, R20). Stage 3: GEMM (f32). Epilogue writes fp16 only.
__launch_bounds__(256, 8)
__global__ void conv_kernel(const float* __restrict__ xinf, const __half* __restrict__ xinh,
                            __half* __restrict__ xouth,
                            const int* __restrict__ prow, const int* __restrict__ bsum,
                            const int* __restrict__ cnt,
                            const int2* __restrict__ epack,
                            const float* __restrict__ Wt,
                            const float* __restrict__ bias, const float* __restrict__ eps,
                            int epsidx, int dorelu, int zerorow0, int selff32,
                            int n, int nchunk) {
  __shared__ float xm[CONV_NPB * 128];
  __shared__ int rp_s[CONV_NPB + 1];
  const int t = threadIdx.x;
  const int nb = blockIdx.x * CONV_NPB;
  const float epsv = 1.0f + eps[epsidx];

#pragma unroll
  for (int i = 0; i < 4; ++i)
    *(float4*)&xm[(t + i * 256) * 4] = make_float4(0.f, 0.f, 0.f, 0.f);
  if (t <= CONV_NPB) {
    const int node = nb + t;
    rp_s[t] = (node >= n) ? bsum[nchunk] : (prow[node] + bsum[node >> 11]);
  }
  __syncthreads();

  // ---- stage 1: padded 8-batch laneset fp16 gather with descriptor prefetch ----
  {
    const int L = t >> 5;
    const int lane = t & 31;
    const int f0 = lane * 4;
    const int e0 = rp_s[0], eT = rp_s[CONV_NPB];
    const int nbat = (eT - e0) >> 3;
    const int chunk = (((nbat + 7) >> 3)) << 3;
    const int jb = e0 + L * chunk;
    const int je = min(jb + chunk, eT);
    if (jb < je) {
      const int4* ep4 = (const int4*)epack;
      int r = 0;
      while (rp_s[r + 1] <= jb) ++r;
      float4 acc = make_float4(0.f, 0.f, 0.f, 0.f);
      // preload first batch's descriptors
      int h = jb >> 1;
      int4 q0 = ep4[h + 0];
      int4 q1 = ep4[h + 1];
      int4 q2 = ep4[h + 2];
      int4 q3 = ep4[h + 3];
      for (int j = jb; j < je; j += 8) {
        if (rp_s[r + 1] <= j) {
          float* bp = &xm[r * 128 + lane];
          atomicAdd(bp + 0,  acc.x);
          atomicAdd(bp + 32, acc.y);
          atomicAdd(bp + 64, acc.z);
          atomicAdd(bp + 96, acc.w);
          acc = make_float4(0.f, 0.f, 0.f, 0.f);
          do { ++r; } while (rp_s[r + 1] <= j);
        }
        // issue the 8 fp16 gathers for THIS batch (addresses already resident)
        const h4 u0 = *(const h4*)&xinh[(size_t)q0.x * 128 + f0];
        const h4 u1 = *(const h4*)&xinh[(size_t)q0.z * 128 + f0];
        const h4 u2 = *(const h4*)&xinh[(size_t)q1.x * 128 + f0];
        const h4 u3 = *(const h4*)&xinh[(size_t)q1.z * 128 + f0];
        const h4 u4 = *(const h4*)&xinh[(size_t)q2.x * 128 + f0];
        const h4 u5 = *(const h4*)&xinh[(size_t)q2.z * 128 + f0];
        const h4 u6 = *(const h4*)&xinh[(size_t)q3.x * 128 + f0];
        const h4 u7 = *(const h4*)&xinh[(size_t)q3.z * 128 + f0];
        const float w0 = __int_as_float(q0.y), w1 = __int_as_float(q0.w);
        const float w2 = __int_as_float(q1.y), w3 = __int_as_float(q1.w);
        const float w4 = __int_as_float(q2.y), w5 = __int_as_float(q2.w);
        const float w6 = __int_as_float(q3.y), w7 = __int_as_float(q3.w);
        // prefetch NEXT batch's descriptors (clamped, branch-free)
        const int jn = (j + 8 < je) ? (j + 8) : j;
        const int hn = jn >> 1;
        q0 = ep4[hn + 0];
        q1 = ep4[hn + 1];
        q2 = ep4[hn + 2];
        q3 = ep4[hn + 3];
        const float4 a0 = h4f(u0), a1 = h4f(u1), a2 = h4f(u2), a3 = h4f(u3);
        const float4 a4 = h4f(u4), a5 = h4f(u5), a6 = h4f(u6), a7 = h4f(u7);
        acc.x += w0 * a0.x + w1 * a1.x + w2 * a2.x + w3 * a3.x
               + w4 * a4.x + w5 * a5.x + w6 * a6.x + w7 * a7.x;
        acc.y += w0 * a0.y + w1 * a1.y + w2 * a2.y + w3 * a3.y
               + w4 * a4.y + w5 * a5.y + w6 * a6.y + w7 * a7.y;
        acc.z += w0 * a0.z + w1 * a1.z + w2 * a2.z + w3 * a3.z
               + w4 * a4.z + w5 * a5.z + w6 * a6.z + w7 * a7.z;
        acc.w += w0 * a0.w + w1 * a1.w + w2 * a2.w + w3 * a3.w
               + w4 * a4.w + w5 * a5.w + w6 * a6.w + w7 * a7.w;
      }
      float* bp = &xm[r * 128 + lane];
      atomicAdd(bp + 0,  acc.x);
      atomicAdd(bp + 32, acc.y);
      atomicAdd(bp + 64, acc.z);
      atomicAdd(bp + 96, acc.w);
    }
  }
  __syncthreads();

  // ---- stage 2: de-permute + finalize (1+eps)*x + agg/deg ----
  {
    float4 m[4];
#pragma unroll
    for (int q = 0; q < 4; ++q) {
      const int task = t + q * 256;
      const int r = task >> 5;
      const int fg = task & 31;
      m[q].x = xm[r * 128 + fg];
      m[q].y = xm[r * 128 + 32 + fg];
      m[q].z = xm[r * 128 + 64 + fg];
      m[q].w = xm[r * 128 + 96 + fg];
    }
    __syncthreads();
#pragma unroll
    for (int q = 0; q < 4; ++q) {
      const int task = t + q * 256;
      const int r = task >> 5;
      const int fg = task & 31;
      const int f0 = fg * 4;
      const int node = nb + r;
      float4 v = make_float4(0.f, 0.f, 0.f, 0.f);
      if (node < n) {
        const int d = cnt[node];
        const float rdeg = 1.0f / (float)(d > 1 ? d : 1);
        float4 xv;
        if (selff32) xv = *(const float4*)&xinf[(size_t)node * 128 + f0];
        else         xv = h4f(*(const h4*)&xinh[(size_t)node * 128 + f0]);
        v.x = epsv * xv.x + m[q].x * rdeg;
        v.y = epsv * xv.y + m[q].y * rdeg;
        v.z = epsv * xv.z + m[q].z * rdeg;
        v.w = epsv * xv.w + m[q].w * rdeg;
      }
      *(float4*)&xm[r * 128 + f0] = v;
    }
  }
  __syncthreads();

  // ---- stage 3: GEMM, thread tile = 4 rows x 4 features ----
  {
    const int fg = t & 31;
    const int rg = t >> 5;
    const int f0 = fg * 4;
    const int r0 = rg * 4;
    float4 acc[4];
#pragma unroll
    for (int r = 0; r < 4; ++r) acc[r] = make_float4(0.f, 0.f, 0.f, 0.f);
    for (int k = 0; k < 128; k += 4) {
      const float4 w0 = *(const float4*)&Wt[(k + 0) * 128 + f0];
      const float4 w1 = *(const float4*)&Wt[(k + 1) * 128 + f0];
      const float4 w2 = *(const float4*)&Wt[(k + 2) * 128 + f0];
      const float4 w3 = *(const float4*)&Wt[(k + 3) * 128 + f0];
#pragma unroll
      for (int r = 0; r < 4; ++r) {
        const float4 xv = *(const float4*)&xm[(r0 + r) * 128 + k];
        acc[r].x += xv.x * w0.x + xv.y * w1.x + xv.z * w2.x + xv.w * w3.x;
        acc[r].y += xv.x * w0.y + xv.y * w1.y + xv.z * w2.y + xv.w * w3.y;
        acc[r].z += xv.x * w0.z + xv.y * w1.z + xv.z * w2.z + xv.w * w3.z;
        acc[r].w += xv.x * w0.w + xv.y * w1.w + xv.z * w2.w + xv.w * w3.w;
      }
    }
    const float4 bv = *(const float4*)&bias[f0];
#pragma unroll
    for (int r = 0; r < 4; ++r) {
      const int node = nb + r0 + r;
      if (node < n) {
        float4 v;
        v.x = acc[r].x + bv.x;
        v.y = acc[r].y + bv.y;
        v.z = acc[r].z + bv.z;
        v.w = acc[r].w + bv.w;
        if (dorelu) {
          v.x = fmaxf(v.x, 0.f); v.y = fmaxf(v.y, 0.f);
          v.z = fmaxf(v.z, 0.f); v.w = fmaxf(v.w, 0.f);
        }
        if (zerorow0 && node == 0) { v.x = 0.f; v.y = 0.f; v.z = 0.f; v.w = 0.f; }
        *(h4*)&xouth[(size_t)node * 128 + f0] = f4h(v);
      }
    }
  }
}

// Final MLP: 8 elems per 256-thread block (512 blocks); x2 gathers in fp16.
__launch_bounds__(256, 4)
__global__ void final_kernel(const __half* __restrict__ x2h, const int* __restrict__ indices,
                             const float* __restrict__ Wc1t, const float* __restrict__ bc1,
                             const float* __restrict__ Wc2t, const float* __restrict__ bc2,
                             const float* __restrict__ Wc3, const float* __restrict__ bc3,
                             float* __restrict__ out) {
  __shared__ float ysm[FIN_EPB * 384];
  __shared__ float h1s[FIN_EPB * 128];
  __shared__ float h2s[FIN_EPB * 64];
  __shared__ int ind_s[FIN_EPB * 23];
  __shared__ float ccs[FIN_EPB];
  const int t = threadIdx.x;
  const int b0 = blockIdx.x * FIN_EPB;

  if (t < FIN_EPB * 23) ind_s[t] = indices[(size_t)b0 * 23 + t];
  __syncthreads();
  if (t < FIN_EPB) {
    int cc = 0;
#pragma unroll
    for (int j = 0; j < 20; ++j) cc += (ind_s[t * 23 + 3 + j] > 0) ? 1 : 0;
    ccs[t] = 1.0f / (float)(cc > 0 ? cc : 1);
  }
  __syncthreads();

  // ---- phase A ----
  {
#pragma unroll
    for (int q = 0; q < 2; ++q) {
      const int s = t + q * 256;
      const int e = s >> 6;
      const int hf = (s >> 5) & 1;
      const int fg = s & 31;
      const int idx = ind_s[e * 23 + hf];
      const h4 u = *(const h4*)&x2h[(size_t)idx * 128 + fg * 4];
      *(float4*)&ysm[e * 384 + hf * 128 + fg * 4] = h4f(u);
    }
    const int e = t >> 5;
    const int fg = t & 31;
    float4 acc = make_float4(0.f, 0.f, 0.f, 0.f);
#pragma unroll
    for (int j = 0; j < 20; ++j) {
      const int cj = ind_s[e * 23 + 3 + j];
      const h4 u = *(const h4*)&x2h[(size_t)cj * 128 + fg * 4];
      const float4 a = h4f(u);
      acc.x += a.x; acc.y += a.y; acc.z += a.z; acc.w += a.w;
    }
    const float sc = ccs[e];
    acc.x *= sc; acc.y *= sc; acc.z *= sc; acc.w *= sc;
    *(float4*)&ysm[e * 384 + 256 + fg * 4] = acc;
  }
  __syncthreads();

  // ---- phase B: layer 1 (384 -> 128), 4 elems per thread ----
  {
    const int f1 = t & 127;
    const int eh = t >> 7;
    float acc[4];
    const float b = bc1[f1];
#pragma unroll
    for (int i = 0; i < 4; ++i) acc[i] = b;
    for (int k = 0; k < 384; k += 4) {
      const float wv0 = Wc1t[(k + 0) * 128 + f1];
      const float wv1 = Wc1t[(k + 1) * 128 + f1];
      const float wv2 = Wc1t[(k + 2) * 128 + f1];
      const float wv3 = Wc1t[(k + 3) * 128 + f1];
#pragma unroll
      for (int i = 0; i < 4; ++i) {
        const float4 yv = *(const float4*)&ysm[(eh * 4 + i) * 384 + k];
        acc[i] += yv.x * wv0 + yv.y * wv1 + yv.z * wv2 + yv.w * wv3;
      }
    }
#pragma unroll
    for (int i = 0; i < 4; ++i)
      h1s[(eh * 4 + i) * 128 + f1] = fmaxf(acc[i], 0.f);
  }
  __syncthreads();

  // ---- phase C: layer 2 (128 -> 64), 2 elems per thread ----
  {
    const int f2 = t & 63;
    const int eg = t >> 6;
    float acc[2];
    const float b = bc2[f2];
#pragma unroll
    for (int i = 0; i < 2; ++i) acc[i] = b;
    for (int k = 0; k < 128; k += 4) {
      const float wv0 = Wc2t[(k + 0) * 64 + f2];
      const float wv1 = Wc2t[(k + 1) * 64 + f2];
      const float wv2 = Wc2t[(k + 2) * 64 + f2];
      const float wv3 = Wc2t[(k + 3) * 64 + f2];
#pragma unroll
      for (int i = 0; i < 2; ++i) {
        const float4 hv = *(const float4*)&h1s[(eg * 2 + i) * 128 + k];
        acc[i] += hv.x * wv0 + hv.y * wv1 + hv.z * wv2 + hv.w * wv3;
      }
    }
#pragma unroll
    for (int i = 0; i < 2; ++i)
      h2s[(eg * 2 + i) * 64 + f2] = fmaxf(acc[i], 0.f);
  }
  __syncthreads();

  // ---- phase D: layer 3 (64 -> 1), 32 lanes per element ----
  {
    const int e = t >> 5;
    const int l = t & 31;
    float p = h2s[e * 64 + l] * Wc3[l] + h2s[e * 64 + l + 32] * Wc3[l + 32];
#pragma unroll
    for (int o = 16; o > 0; o >>= 1) p += __shfl_down(p, o, 32);
    if (l == 0) out[b0 + e] = p + bc3[0];
  }
}

extern "C" void kernel_launch(void* const* d_in, const int* in_sizes, int n_in,
                              void* d_out, int out_size, void* d_ws, size_t ws_size,
                              hipStream_t stream) {
  const int* indices = (const int*)d_in[0];
  const int* src = (const int*)d_in[1];
  const int* dst = (const int*)d_in[2];
  const float* w = (const float*)d_in[3];
  const float* ndata = (const float*)d_in[4];
  const float* W1 = (const float*)d_in[5];
  const float* b1 = (const float*)d_in[6];
  const float* W2 = (const float*)d_in[7];
  const float* b2 = (const float*)d_in[8];
  const float* eps = (const float*)d_in[9];
  const float* Wc1 = (const float*)d_in[10];
  const float* bc1 = (const float*)d_in[11];
  const float* Wc2 = (const float*)d_in[12];
  const float* bc2 = (const float*)d_in[13];
  const float* Wc3 = (const float*)d_in[14];
  const float* bc3 = (const float*)d_in[15];
  float* out = (float*)d_out;

  const int E = in_sizes[1];
  const int N = in_sizes[4] / 128;
  const int B = in_sizes[0] / 23;

  char* ws = (char*)d_ws;
  size_t off = 0;
  auto alloc = [&](size_t bytes) -> char* {
    char* p = ws + off;
    off = (off + bytes + 255) & ~(size_t)255;
    return p;
  };
  const size_t Epad = (size_t)E + 8 * (size_t)N;   // worst-case padded edge count
  int* cnt = (int*)alloc((size_t)N * 4);
  int* prow = (int*)alloc((size_t)(N + 1) * 4);
  int* rank = (int*)alloc((size_t)E * 4);
  int* bsum = (int*)alloc(256 * 4);
  int2* epack = (int2*)alloc(Epad * 8);
  __half* xh0 = (__half*)alloc((size_t)N * 128 * 2);       // fp16 ndata; reused as x2h
  __half* x1h = (__half*)alloc((size_t)N * 128 * 2);       // fp16 x1
  float* Wt1 = (float*)alloc(16384 * 4);
  float* Wt2 = (float*)alloc(16384 * 4);
  float* Wc1t = (float*)alloc(49152 * 4);
  float* Wc2t = (float*)alloc(8192 * 4);
  __half* x2h = xh0;   // xh0 dead after conv1; conv2 writes x2 (fp16) here

  // cnt = 0 (stream-ordered; completes before inithist's atomics)
  hipMemsetAsync(cnt, 0, (size_t)N * 4, stream);

  const int ncast = (N * 128 + 7) / 8;                     // 1.6M cast threads
  const int Eq = (E + 3) / 4;
  int ninit = (N > 90112) ? N : 90112;
  if (ncast > ninit) ninit = ncast;
  if (Eq > ninit) ninit = Eq;
  inithist_kernel<<<(ninit + 255) / 256, 256, 0, stream>>>(
      W1, W2, Wc1, Wc2, ndata, xh0, Wt1, Wt2, Wc1t, Wc2t, dst, cnt, rank, N, E);

  const int nchunk = (N + 2047) / 2048;
  scan1_kernel<<<nchunk, 256, 0, stream>>>(cnt, prow, bsum, N);
  scan2_kernel<<<1, 64, 0, stream>>>(bsum, nchunk);
  const int nsc = (Eq > N) ? Eq : N;
  scatter_kernel<<<(nsc + 255) / 256, 256, 0, stream>>>(src, dst, w, prow, bsum, rank, cnt, epack, E, N);

  const int nconv = (N + CONV_NPB - 1) / CONV_NPB;
  // conv1: gathers fp16(ndata); self term f32 ndata; writes x1h (fp16 only)
  conv_kernel<<<nconv, 256, 0, stream>>>(ndata, xh0, x1h, prow, bsum, cnt, epack,
                                         Wt1, b1, eps, 0, 1, 0, 1, N, nchunk);
  // conv2: gathers x1h; self term fp16 x1h; writes x2h (into xh0 buffer)
  conv_kernel<<<nconv, 256, 0, stream>>>(nullptr, x1h, x2h, prow, bsum, cnt, epack,
                                         Wt2, b2, eps, 1, 0, 1, 0, N, nchunk);

  final_kernel<<<B / FIN_EPB, 256, 0, stream>>>(x2h, indices, Wc1t, bc1, Wc2t, bc2, Wc3, bc3, out);
}